// Round 1
// baseline (887.943 us; speedup 1.0000x reference)
//
#include <hip/hip_runtime.h>

// ---------------------------------------------------------------------------
// ScaledDotProductAttention: B=8, Sq=Sk=2048, D=E=1024, f32 in/out.
//   WQ = rnn_ht @ W; WK = Lt @ k0; WV = Lt @ k1
//   QK = WQ @ WK^T * 0.125; P = softmax(QK); ctx = P @ WV
// Outputs: d_out = [ctx (16777216 f32)] ++ [P (33554432 f32)]
// Strategy: bf16 MFMA for all GEMMs (2%-of-max threshold permits), all GEMMs
// in NT form C[m,n] = sum_k A[m,k]*B[n,k] via pre-transposed weight matrices
// and a transposed-V projection (WVt[e,k]).
// ---------------------------------------------------------------------------

typedef __bf16 bf16x8 __attribute__((ext_vector_type(8)));
typedef __bf16 bf16x4 __attribute__((ext_vector_type(4)));
typedef float  f32x4  __attribute__((ext_vector_type(4)));

__device__ __forceinline__ void gload_lds16(const void* g, void* l) {
  __builtin_amdgcn_global_load_lds(
      (__attribute__((address_space(1))) void*)(g),
      (__attribute__((address_space(3))) void*)(uintptr_t)(l),
      16, 0, 0);
}

// ---------------------------------------------------------------------------
// NT GEMM: C[m,n] = sum_k A[m,k] * B[n,k].  M,N mult of 128, K mult of 32.
// AF32/BF32: operand is f32 in global, converted to bf16 during LDS staging.
// OUTBF16: write bf16 (no scale) else f32 * scale.
// 256 threads = 4 waves (2x2), each wave does 64x64 via 4x4 MFMA 16x16x32.
// ---------------------------------------------------------------------------
template <bool AF32, bool BF32, bool OUTBF16>
__global__ __launch_bounds__(256)
void gemm_nt(const void* __restrict__ Ap, const void* __restrict__ Bp,
             void* __restrict__ Cp, int M, int N, int K,
             unsigned long long sAb, unsigned long long sBb,
             unsigned long long sCb, float scale) {
  __shared__ __bf16 As[128 * 32];
  __shared__ __bf16 Bs[128 * 32];

  const int tid  = threadIdx.x;
  const int wave = tid >> 6;
  const int lane = tid & 63;
  const int wm   = (wave >> 1) * 64;   // wave row offset in tile
  const int wn   = (wave & 1) * 64;    // wave col offset in tile
  const size_t m0 = (size_t)blockIdx.y * 128;
  const size_t n0 = (size_t)blockIdx.x * 128;
  const size_t z  = blockIdx.z;

  f32x4 acc[4][4] = {};

  // bf16 fast path staging indices: wave stages rows [wave*32, wave*32+32)
  const int glr = lane >> 2;        // row within 16-row chunk
  const int glc = (lane & 3) * 8;   // elem col (8 bf16 = 16B)
  // f32 cvt path staging indices: 256 threads cover 32 rows x 32 cols per iter
  const int fr = tid >> 3;          // 0..31
  const int fc = (tid & 7) * 4;     // 0,4,..28

  for (int kt = 0; kt < K; kt += 32) {
    // ---- stage A tile (128 x 32) ----
    if constexpr (!AF32) {
      const __bf16* Ah = (const __bf16*)Ap + z * sAb;
#pragma unroll
      for (int i = 0; i < 2; ++i) {
        const int rbase = wave * 32 + i * 16;
        gload_lds16(Ah + (m0 + rbase + glr) * (size_t)K + kt + glc,
                    &As[rbase * 32]);
      }
    } else {
      const float* Af = (const float*)Ap + z * sAb;
#pragma unroll
      for (int i = 0; i < 4; ++i) {
        const int r = i * 32 + fr;
        float4 f = *(const float4*)(Af + (m0 + r) * (size_t)K + kt + fc);
        bf16x4 h = {(__bf16)f.x, (__bf16)f.y, (__bf16)f.z, (__bf16)f.w};
        *(bf16x4*)&As[r * 32 + fc] = h;
      }
    }
    // ---- stage B tile (128 x 32) ----
    if constexpr (!BF32) {
      const __bf16* Bh = (const __bf16*)Bp + z * sBb;
#pragma unroll
      for (int i = 0; i < 2; ++i) {
        const int rbase = wave * 32 + i * 16;
        gload_lds16(Bh + (n0 + rbase + glr) * (size_t)K + kt + glc,
                    &Bs[rbase * 32]);
      }
    } else {
      const float* Bf = (const float*)Bp + z * sBb;
#pragma unroll
      for (int i = 0; i < 4; ++i) {
        const int r = i * 32 + fr;
        float4 f = *(const float4*)(Bf + (n0 + r) * (size_t)K + kt + fc);
        bf16x4 h = {(__bf16)f.x, (__bf16)f.y, (__bf16)f.z, (__bf16)f.w};
        *(bf16x4*)&Bs[r * 32 + fc] = h;
      }
    }
    __syncthreads();

    // ---- MFMA phase ----
    const int fm = lane & 15;
    const int kq = (lane >> 4) * 8;
    bf16x8 afr[4], bfr[4];
#pragma unroll
    for (int i = 0; i < 4; ++i)
      afr[i] = *(const bf16x8*)&As[(wm + i * 16 + fm) * 32 + kq];
#pragma unroll
    for (int j = 0; j < 4; ++j)
      bfr[j] = *(const bf16x8*)&Bs[(wn + j * 16 + fm) * 32 + kq];
#pragma unroll
    for (int i = 0; i < 4; ++i)
#pragma unroll
      for (int j = 0; j < 4; ++j)
        acc[i][j] = __builtin_amdgcn_mfma_f32_16x16x32_bf16(afr[i], bfr[j],
                                                            acc[i][j], 0, 0, 0);
    __syncthreads();
  }

  // ---- epilogue: C/D layout col=lane&15, row=(lane>>4)*4+reg ----
  const int col   = lane & 15;
  const int rquad = (lane >> 4) * 4;
#pragma unroll
  for (int i = 0; i < 4; ++i) {
#pragma unroll
    for (int r = 0; r < 4; ++r) {
      const size_t row = m0 + wm + i * 16 + rquad + r;
#pragma unroll
      for (int j = 0; j < 4; ++j) {
        const size_t cidx = z * sCb + row * (size_t)N + n0 + wn + j * 16 + col;
        if constexpr (OUTBF16) {
          ((__bf16*)Cp)[cidx] = (__bf16)acc[i][j][r];
        } else {
          ((float*)Cp)[cidx] = acc[i][j][r] * scale;
        }
      }
    }
  }
}

// ---------------------------------------------------------------------------
// cvt+transpose 1024x1024 f32 -> bf16 (out[n,d] = in[d,n]); z selects matrix
// ---------------------------------------------------------------------------
__global__ __launch_bounds__(256)
void cvt_transpose(const float* __restrict__ s0, const float* __restrict__ s1,
                   const float* __restrict__ s2, __bf16* __restrict__ d0,
                   __bf16* __restrict__ d1, __bf16* __restrict__ d2) {
  const float* s = blockIdx.z == 0 ? s0 : (blockIdx.z == 1 ? s1 : s2);
  __bf16* d      = blockIdx.z == 0 ? d0 : (blockIdx.z == 1 ? d1 : d2);
  __shared__ float tile[32][33];
  const int x  = blockIdx.x * 32 + threadIdx.x;
  const int y0 = blockIdx.y * 32;
  for (int j = threadIdx.y; j < 32; j += 8)
    tile[j][threadIdx.x] = s[(size_t)(y0 + j) * 1024 + x];
  __syncthreads();
  const int x2 = y0 + threadIdx.x;
  const int y2 = blockIdx.x * 32;
  for (int j = threadIdx.y; j < 32; j += 8)
    d[(size_t)(y2 + j) * 1024 + x2] = (__bf16)tile[threadIdx.x][j];
}

// ---------------------------------------------------------------------------
// row softmax in place: 16384 rows x 2048 f32, one block per row
// ---------------------------------------------------------------------------
__global__ __launch_bounds__(256)
void softmax_rows(float* __restrict__ Wt) {
  const int t = threadIdx.x;
  float* p = Wt + (size_t)blockIdx.x * 2048;
  float4 a = ((float4*)p)[t];
  float4 b = ((float4*)p)[t + 256];

  float m = fmaxf(fmaxf(fmaxf(a.x, a.y), fmaxf(a.z, a.w)),
                  fmaxf(fmaxf(b.x, b.y), fmaxf(b.z, b.w)));
#pragma unroll
  for (int off = 32; off > 0; off >>= 1) m = fmaxf(m, __shfl_xor(m, off));
  __shared__ float red[8];
  if ((t & 63) == 0) red[t >> 6] = m;
  __syncthreads();
  m = fmaxf(fmaxf(red[0], red[1]), fmaxf(red[2], red[3]));

  a.x = __expf(a.x - m); a.y = __expf(a.y - m);
  a.z = __expf(a.z - m); a.w = __expf(a.w - m);
  b.x = __expf(b.x - m); b.y = __expf(b.y - m);
  b.z = __expf(b.z - m); b.w = __expf(b.w - m);
  float s = a.x + a.y + a.z + a.w + b.x + b.y + b.z + b.w;
#pragma unroll
  for (int off = 32; off > 0; off >>= 1) s += __shfl_xor(s, off);
  if ((t & 63) == 0) red[4 + (t >> 6)] = s;
  __syncthreads();
  s = red[4] + red[5] + red[6] + red[7];

  const float inv = 1.0f / s;
  a.x *= inv; a.y *= inv; a.z *= inv; a.w *= inv;
  b.x *= inv; b.y *= inv; b.z *= inv; b.w *= inv;
  ((float4*)p)[t] = a;
  ((float4*)p)[t + 256] = b;
}

// ---------------------------------------------------------------------------
extern "C" void kernel_launch(void* const* d_in, const int* in_sizes, int n_in,
                              void* d_out, int out_size, void* d_ws,
                              size_t ws_size, hipStream_t stream) {
  const float* Lt  = (const float*)d_in[0];  // [8,2048,1024]
  const float* rnn = (const float*)d_in[1];  // [8,2048,1024]
  const float* ker = (const float*)d_in[2];  // [2,1024,1024]
  const float* W   = (const float*)d_in[3];  // [1024,1024]

  float* ctx = (float*)d_out;                // [8,2048,1024]
  float* wts = ctx + (size_t)16777216;       // [8,2048,2048]

  __bf16* ws  = (__bf16*)d_ws;
  __bf16* Wt  = ws;                          // [1024,1024]  (n,d)
  __bf16* k0t = Wt + (1u << 20);             // [1024,1024]
  __bf16* k1t = k0t + (1u << 20);            // [1024,1024]
  __bf16* WQ  = k1t + (1u << 20);            // [8*2048,1024]
  __bf16* WK  = WQ + (16u << 20);            // [8*2048,1024]
  __bf16* WVt = WK + (16u << 20);            // [8][1024][2048]  (e,k)

  // 1) transpose + cvt the three weight matrices
  cvt_transpose<<<dim3(32, 32, 3), dim3(32, 8), 0, stream>>>(
      W, ker, ker + (1u << 20), Wt, k0t, k1t);

  // 2) projections (NT): WQ = rnn @ Wt^T-contract, WK = Lt @ k0t
  gemm_nt<true, false, true><<<dim3(8, 128, 1), 256, 0, stream>>>(
      rnn, Wt, WQ, 16384, 1024, 1024, 0ull, 0ull, 0ull, 1.0f);
  gemm_nt<true, false, true><<<dim3(8, 128, 1), 256, 0, stream>>>(
      Lt, k0t, WK, 16384, 1024, 1024, 0ull, 0ull, 0ull, 1.0f);

  // 3) WVt[b][e][k] = sum_d k1t[e,d] * Lt[b,k,d]  (NT, batched)
  gemm_nt<false, true, true><<<dim3(16, 8, 8), 256, 0, stream>>>(
      k1t, Lt, WVt, 1024, 2048, 1024, 0ull, 2048ull * 1024ull,
      1024ull * 2048ull, 1.0f);

  // 4) QK logits (pure bf16 path), *0.125, f32 -> weights region of d_out
  gemm_nt<false, false, false><<<dim3(16, 16, 8), 256, 0, stream>>>(
      WQ, WK, wts, 2048, 2048, 1024, 2048ull * 1024ull, 2048ull * 1024ull,
      2048ull * 2048ull, 0.125f);

  // 5) softmax rows in place
  softmax_rows<<<16384, 256, 0, stream>>>(wts);

  // 6) ctx[b,q,e] = sum_k P[b,q,k] * WVt[b,e,k]  (A f32 cvt-on-load)
  gemm_nt<true, false, false><<<dim3(8, 16, 8), 256, 0, stream>>>(
      wts, WVt, ctx, 2048, 1024, 2048, 2048ull * 2048ull, 1024ull * 2048ull,
      2048ull * 1024ull, 1.0f);
}

// Round 2
// 708.640 us; speedup vs baseline: 1.2530x; 1.2530x over previous
//
#include <hip/hip_runtime.h>

// ---------------------------------------------------------------------------
// ScaledDotProductAttention: B=8, Sq=Sk=2048, D=E=1024, f32 in/out.
// Round 2: BK=64 (half the barrier rounds), XOR-granule LDS swizzle
// (conflict-free ds_read_b128), XCD-aware block swizzle for L2 locality.
// ---------------------------------------------------------------------------

typedef __bf16 bf16x8 __attribute__((ext_vector_type(8)));
typedef __bf16 bf16x4 __attribute__((ext_vector_type(4)));
typedef float  f32x4  __attribute__((ext_vector_type(4)));

__device__ __forceinline__ void gload_lds16(const void* g, void* l) {
  __builtin_amdgcn_global_load_lds(
      (__attribute__((address_space(1))) void*)(g),
      (__attribute__((address_space(3))) void*)(uintptr_t)(l),
      16, 0, 0);
}

// LDS tile: 128 rows x 64 bf16 cols = 128B rows = 8 granules of 16B.
// Granule g of row r lives at position g ^ (r & 7)  -> bank-conflict-free
// for both row-wise staging and 16-consecutive-row fragment reads.
__device__ __forceinline__ int swz(int r, int g) {
  return r * 64 + ((g ^ (r & 7)) << 3);
}

// ---------------------------------------------------------------------------
// NT GEMM: C[m,n] = sum_k A[m,k]*B[n,k].  M,N mult of 128, K mult of 64.
// AF32/BF32: operand is f32 in global, cvt to bf16 during LDS staging.
// 256 threads = 4 waves (2x2), wave does 64x64 via 4x4 MFMA 16x16x32,
// two k-half passes per BK=64 tile.
// ---------------------------------------------------------------------------
template <bool AF32, bool BF32, bool OUTBF16>
__global__ __launch_bounds__(256)
void gemm_nt(const void* __restrict__ Ap, const void* __restrict__ Bp,
             void* __restrict__ Cp, int M, int N, int K,
             unsigned long long sAb, unsigned long long sBb,
             unsigned long long sCb, float scale) {
  __shared__ __bf16 As[128 * 64];
  __shared__ __bf16 Bs[128 * 64];

  const int tid  = threadIdx.x;
  const int wave = tid >> 6;
  const int lane = tid & 63;
  const int wm   = (wave >> 1) * 64;
  const int wn   = (wave & 1) * 64;

  // ---- XCD/L2-aware block swizzle ----
  int bx, by, bz;
  {
    const int nx = gridDim.x, ny = gridDim.y;
    const int d = blockIdx.x + nx * (blockIdx.y + ny * blockIdx.z);
    if (gridDim.z == 8 && ((nx * ny) & 63) == 0 && (nx & 7) == 0) {
      bz = d & 7;                       // one batch per XCD (heuristic)
      const int s = d >> 3;
      const int sq = s >> 6, w = s & 63;  // 8x8 squares within the batch grid
      const int nsx = nx >> 3;
      const int sqx = sq % nsx, sqy = sq / nsx;
      bx = sqx * 8 + (w & 7);
      by = sqy * 8 + (w >> 3);
    } else {
      bx = blockIdx.x; by = blockIdx.y; bz = blockIdx.z;
    }
  }
  const size_t m0 = (size_t)by * 128;
  const size_t n0 = (size_t)bx * 128;
  const size_t z  = bz;

  f32x4 acc[4][4] = {};

  const int fm = lane & 15;

  for (int kt = 0; kt < K; kt += 64) {
    // ---- stage A tile (128 x 64 bf16) ----
    if constexpr (!AF32) {
      const __bf16* Ab = (const __bf16*)Ap + z * sAb;
#pragma unroll
      for (int i = 0; i < 4; ++i) {
        const int c = wave * 4 + i;        // 8-row chunk (1 KB LDS)
        const int r = c * 8 + (lane >> 3);
        const int g = (lane & 7) ^ (r & 7);
        gload_lds16(Ab + (m0 + r) * (size_t)K + kt + g * 8, &As[c * 512]);
      }
    } else {
      const float* Af = (const float*)Ap + z * sAb;
#pragma unroll
      for (int i = 0; i < 8; ++i) {
        const int r = i * 16 + (tid >> 4);
        const int col = (tid & 15) * 4;
        float4 f = *(const float4*)(Af + (m0 + r) * (size_t)K + kt + col);
        bf16x4 h = {(__bf16)f.x, (__bf16)f.y, (__bf16)f.z, (__bf16)f.w};
        const int g = col >> 3;
        *(bf16x4*)&As[r * 64 + (((g ^ (r & 7)) << 3) | (col & 7))] = h;
      }
    }
    // ---- stage B tile (128 x 64 bf16) ----
    if constexpr (!BF32) {
      const __bf16* Bb = (const __bf16*)Bp + z * sBb;
#pragma unroll
      for (int i = 0; i < 4; ++i) {
        const int c = wave * 4 + i;
        const int r = c * 8 + (lane >> 3);
        const int g = (lane & 7) ^ (r & 7);
        gload_lds16(Bb + (n0 + r) * (size_t)K + kt + g * 8, &Bs[c * 512]);
      }
    } else {
      const float* Bf = (const float*)Bp + z * sBb;
#pragma unroll
      for (int i = 0; i < 8; ++i) {
        const int r = i * 16 + (tid >> 4);
        const int col = (tid & 15) * 4;
        float4 f = *(const float4*)(Bf + (n0 + r) * (size_t)K + kt + col);
        bf16x4 h = {(__bf16)f.x, (__bf16)f.y, (__bf16)f.z, (__bf16)f.w};
        const int g = col >> 3;
        *(bf16x4*)&Bs[r * 64 + (((g ^ (r & 7)) << 3) | (col & 7))] = h;
      }
    }
    __syncthreads();

    // ---- MFMA: two k-half passes (k32 each) ----
#pragma unroll
    for (int h = 0; h < 2; ++h) {
      const int gq = (lane >> 4) + h * 4;  // 16B granule index of this lane's k8
      bf16x8 afr[4], bfr[4];
#pragma unroll
      for (int i = 0; i < 4; ++i)
        afr[i] = *(const bf16x8*)&As[swz(wm + i * 16 + fm, gq)];
#pragma unroll
      for (int j = 0; j < 4; ++j)
        bfr[j] = *(const bf16x8*)&Bs[swz(wn + j * 16 + fm, gq)];
#pragma unroll
      for (int i = 0; i < 4; ++i)
#pragma unroll
        for (int j = 0; j < 4; ++j)
          acc[i][j] = __builtin_amdgcn_mfma_f32_16x16x32_bf16(
              afr[i], bfr[j], acc[i][j], 0, 0, 0);
    }
    __syncthreads();
  }

  // ---- epilogue: C/D layout col=lane&15, row=(lane>>4)*4+reg ----
  const int col   = lane & 15;
  const int rquad = (lane >> 4) * 4;
#pragma unroll
  for (int i = 0; i < 4; ++i) {
#pragma unroll
    for (int r = 0; r < 4; ++r) {
      const size_t row = m0 + wm + i * 16 + rquad + r;
#pragma unroll
      for (int j = 0; j < 4; ++j) {
        const size_t cidx = z * sCb + row * (size_t)N + n0 + wn + j * 16 + col;
        if constexpr (OUTBF16) {
          ((__bf16*)Cp)[cidx] = (__bf16)acc[i][j][r];
        } else {
          ((float*)Cp)[cidx] = acc[i][j][r] * scale;
        }
      }
    }
  }
}

// ---------------------------------------------------------------------------
// cvt+transpose 1024x1024 f32 -> bf16 (out[n,d] = in[d,n]); z selects matrix
// ---------------------------------------------------------------------------
__global__ __launch_bounds__(256)
void cvt_transpose(const float* __restrict__ s0, const float* __restrict__ s1,
                   const float* __restrict__ s2, __bf16* __restrict__ d0,
                   __bf16* __restrict__ d1, __bf16* __restrict__ d2) {
  const float* s = blockIdx.z == 0 ? s0 : (blockIdx.z == 1 ? s1 : s2);
  __bf16* d      = blockIdx.z == 0 ? d0 : (blockIdx.z == 1 ? d1 : d2);
  __shared__ float tile[32][33];
  const int x  = blockIdx.x * 32 + threadIdx.x;
  const int y0 = blockIdx.y * 32;
  for (int j = threadIdx.y; j < 32; j += 8)
    tile[j][threadIdx.x] = s[(size_t)(y0 + j) * 1024 + x];
  __syncthreads();
  const int x2 = y0 + threadIdx.x;
  const int y2 = blockIdx.x * 32;
  for (int j = threadIdx.y; j < 32; j += 8)
    d[(size_t)(y2 + j) * 1024 + x2] = (__bf16)tile[threadIdx.x][j];
}

// ---------------------------------------------------------------------------
// row softmax in place: 16384 rows x 2048 f32, one block per row
// ---------------------------------------------------------------------------
__global__ __launch_bounds__(256)
void softmax_rows(float* __restrict__ Wt) {
  const int t = threadIdx.x;
  float* p = Wt + (size_t)blockIdx.x * 2048;
  float4 a = ((float4*)p)[t];
  float4 b = ((float4*)p)[t + 256];

  float m = fmaxf(fmaxf(fmaxf(a.x, a.y), fmaxf(a.z, a.w)),
                  fmaxf(fmaxf(b.x, b.y), fmaxf(b.z, b.w)));
#pragma unroll
  for (int off = 32; off > 0; off >>= 1) m = fmaxf(m, __shfl_xor(m, off));
  __shared__ float red[8];
  if ((t & 63) == 0) red[t >> 6] = m;
  __syncthreads();
  m = fmaxf(fmaxf(red[0], red[1]), fmaxf(red[2], red[3]));

  a.x = __expf(a.x - m); a.y = __expf(a.y - m);
  a.z = __expf(a.z - m); a.w = __expf(a.w - m);
  b.x = __expf(b.x - m); b.y = __expf(b.y - m);
  b.z = __expf(b.z - m); b.w = __expf(b.w - m);
  float s = a.x + a.y + a.z + a.w + b.x + b.y + b.z + b.w;
#pragma unroll
  for (int off = 32; off > 0; off >>= 1) s += __shfl_xor(s, off);
  if ((t & 63) == 0) red[4 + (t >> 6)] = s;
  __syncthreads();
  s = red[4] + red[5] + red[6] + red[7];

  const float inv = 1.0f / s;
  a.x *= inv; a.y *= inv; a.z *= inv; a.w *= inv;
  b.x *= inv; b.y *= inv; b.z *= inv; b.w *= inv;
  ((float4*)p)[t] = a;
  ((float4*)p)[t + 256] = b;
}

// ---------------------------------------------------------------------------
extern "C" void kernel_launch(void* const* d_in, const int* in_sizes, int n_in,
                              void* d_out, int out_size, void* d_ws,
                              size_t ws_size, hipStream_t stream) {
  const float* Lt  = (const float*)d_in[0];  // [8,2048,1024]
  const float* rnn = (const float*)d_in[1];  // [8,2048,1024]
  const float* ker = (const float*)d_in[2];  // [2,1024,1024]
  const float* W   = (const float*)d_in[3];  // [1024,1024]

  float* ctx = (float*)d_out;                // [8,2048,1024]
  float* wts = ctx + (size_t)16777216;       // [8,2048,2048]

  __bf16* ws  = (__bf16*)d_ws;
  __bf16* Wt  = ws;                          // [1024,1024]  (n,d)
  __bf16* k0t = Wt + (1u << 20);             // [1024,1024]
  __bf16* k1t = k0t + (1u << 20);            // [1024,1024]
  __bf16* WQ  = k1t + (1u << 20);            // [8*2048,1024]
  __bf16* WK  = WQ + (16u << 20);            // [8*2048,1024]
  __bf16* WVt = WK + (16u << 20);            // [8][1024][2048]  (e,k)

  // 1) transpose + cvt the three weight matrices
  cvt_transpose<<<dim3(32, 32, 3), dim3(32, 8), 0, stream>>>(
      W, ker, ker + (1u << 20), Wt, k0t, k1t);

  // 2) projections (NT): WQ = rnn @ Wt, WK = Lt @ k0t
  gemm_nt<true, false, true><<<dim3(8, 128, 1), 256, 0, stream>>>(
      rnn, Wt, WQ, 16384, 1024, 1024, 0ull, 0ull, 0ull, 1.0f);
  gemm_nt<true, false, true><<<dim3(8, 128, 1), 256, 0, stream>>>(
      Lt, k0t, WK, 16384, 1024, 1024, 0ull, 0ull, 0ull, 1.0f);

  // 3) WVt[b][e][k] = sum_d k1t[e,d] * Lt[b,k,d]  (NT, batched)
  gemm_nt<false, true, true><<<dim3(16, 8, 8), 256, 0, stream>>>(
      k1t, Lt, WVt, 1024, 2048, 1024, 0ull, 2048ull * 1024ull,
      1024ull * 2048ull, 1.0f);

  // 4) QK logits (pure bf16 path), *0.125, f32 -> weights region of d_out
  gemm_nt<false, false, false><<<dim3(16, 16, 8), 256, 0, stream>>>(
      WQ, WK, wts, 2048, 2048, 1024, 2048ull * 1024ull, 2048ull * 1024ull,
      2048ull * 2048ull, 0.125f);

  // 5) softmax rows in place
  softmax_rows<<<16384, 256, 0, stream>>>(wts);

  // 6) ctx[b,q,e] = sum_k P[b,q,k] * WVt[b,e,k]  (A f32 cvt-on-load)
  gemm_nt<true, false, false><<<dim3(8, 16, 8), 256, 0, stream>>>(
      wts, WVt, ctx, 2048, 1024, 2048, 2048ull * 2048ull, 1024ull * 2048ull,
      2048ull * 1024ull, 1.0f);
}